// Round 1
// baseline (712.402 us; speedup 1.0000x reference)
//
#include <hip/hip_runtime.h>

// GHMC loss, round 6: replace the per-element LDS read-modify-write
// (ds_read -> lgkmcnt wait -> v_add -> ds_write, a full LDS round-trip on
// the critical path, serialized hardest on the ~42%-hit discard slot) with
// fire-and-forget ds_add_f32 via atomicAdd on the thread-private LDS slot.
// Same-thread LDS ops execute in order -> bit-identical accumulation.
// Also: static A/B ping-pong prefetch (kills 32 v_mov per 16 elems).
//   loss = sum_b (S_b / C_b) / n_nonempty   (tot cancels algebraically)

#define THREADS 256
#define LSTRIDE 11   // 10 bins + discard slot per thread
#define NB 10
#define PF 4         // prefetch group: 4 float4-pairs in flight

__device__ __forceinline__ float bce(float x, float t) {
    // max(x,0) - x*t + log1p(exp(-|x|)); hw v_exp/v_log ~2ulp, negligible
    return fmaxf(x, 0.0f) - x * t + __logf(1.0f + __expf(-fabsf(x)));
}

__global__ __launch_bounds__(THREADS) void ghmc_partial(
    const float4* __restrict__ p4, const float4* __restrict__ t4, int n4,
    const float* __restrict__ p1, const float* __restrict__ t1, long long ntot,
    double* __restrict__ g_sum, unsigned int* __restrict__ g_cnt) {

    __shared__ float lds[THREADS * LSTRIDE];
    const int tid = threadIdx.x;
    float* slots = &lds[tid * LSTRIDE];  // stride 11: <=2-way bank alias, free
#pragma unroll
    for (int b = 0; b < LSTRIDE; ++b) slots[b] = 0.0f;
    // no barrier: regions thread-private; LDS pipe in-order per wave

    const float EDGE10 = 1.0f + 1e-6f;   // f32(edges[-1]) in the reference
    // 4 packed counters (one per float4 component): 10 six-bit fields each;
    // invalid elems go to bits 60..63 (never read). Flush before any field
    // can reach 63 increments (see fcnt logic: worst case 56 in-loop, +4 tail).
    unsigned long long cc[4] = {0ull, 0ull, 0ull, 0ull};
    unsigned cnt[NB];
#pragma unroll
    for (int b = 0; b < NB; ++b) cnt[b] = 0u;

    // trunc(g*10) matches f32 searchsorted edges exactly (verified r3/r4,
    // absmax 0); g in [1.0,1+1e-6) -> idx 10 -> clamp 9 = reference bin 9.
    auto put = [&](float x, float t, unsigned long long& c) {
        const float g = fabsf(x - t);
        const float l = bce(x, t);
        int idx = (int)(g * 10.0f);
        idx = idx > 9 ? 9 : idx;
        idx = (g < EDGE10) ? idx : 10;
        c += 1ull << (6 * idx);
        atomicAdd(&slots[idx], l);       // ds_add_f32, no return, no RAW stall
    };
    auto flush_all = [&]() {
#pragma unroll
        for (int q = 0; q < 4; ++q) {
#pragma unroll
            for (int b = 0; b < NB; ++b)
                cnt[b] += (unsigned)((cc[q] >> (6 * b)) & 63ull);
            cc[q] = 0ull;
        }
    };

    // ---- block-contiguous partitioning ----
    const int chunk = (n4 + (int)gridDim.x - 1) / (int)gridDim.x;
    const int start = blockIdx.x * chunk;
    const int end = min(start + chunk, n4);
    const int count = max(end - start, 0);
    const int full = count / THREADS;        // full block-strided iters (32)
    const int ngrp = full / PF;              // prefetch groups (8)

    float4 PA[PF], TA[PF], PB[PF], TB[PF];
    auto loadg = [&](float4 (&Pd)[PF], float4 (&Td)[PF], int grp) {
#pragma unroll
        for (int g = 0; g < PF; ++g) {
            const int id = start + grp * PF * THREADS + g * THREADS + tid;
            Pd[g] = p4[id]; Td[g] = t4[id];
        }
    };
    auto proc = [&](float4 (&Pd)[PF], float4 (&Td)[PF]) {
#pragma unroll
        for (int g = 0; g < PF; ++g) {
            put(Pd[g].x, Td[g].x, cc[0]);
            put(Pd[g].y, Td[g].y, cc[1]);
            put(Pd[g].z, Td[g].z, cc[2]);
            put(Pd[g].w, Td[g].w, cc[3]);
        }
    };

    // static A/B ping-pong: every buffer index compile-time (no scratch),
    // one full proc (~hundreds of cycles) hides each group's HBM latency.
    int fcnt = 0;
    if (ngrp > 0) loadg(PA, TA, 0);
    int g2 = 0;
    for (; g2 + 2 <= ngrp; g2 += 2) {
        loadg(PB, TB, g2 + 1);
        proc(PA, TA);
        if (g2 + 2 < ngrp) loadg(PA, TA, g2 + 2);
        proc(PB, TB);
        fcnt += 2 * PF;
        if (fcnt >= 56) { flush_all(); fcnt = 0; }  // never taken at ngrp=8
    }
    if (g2 < ngrp) proc(PA, TA);             // odd ngrp tail (not taken here)

    // leftover full iters (full % PF) — not taken for this shape
    for (int k = ngrp * PF; k < full; ++k) {
        const int id = start + k * THREADS + tid;
        const float4 pp = p4[id], tt = t4[id];
        put(pp.x, tt.x, cc[0]); put(pp.y, tt.y, cc[1]);
        put(pp.z, tt.z, cc[2]); put(pp.w, tt.w, cc[3]);
    }
    // tail float4s within the chunk — not taken for this shape
    {
        const int id = start + full * THREADS + tid;
        if (id < end) {
            const float4 pp = p4[id], tt = t4[id];
            put(pp.x, tt.x, cc[0]); put(pp.y, tt.y, cc[1]);
            put(pp.z, tt.z, cc[2]); put(pp.w, tt.w, cc[3]);
        }
    }
    flush_all();

    // scalar tail for ntot % 4 (not taken here): direct global atomics
    if (blockIdx.x == 0 && tid == 0) {
        for (long long j = (long long)n4 * 4; j < ntot; ++j) {
            const float x = p1[j], tt = t1[j];
            const float g = fabsf(x - tt);
            if (g < EDGE10) {
                int idx = (int)(g * 10.0f);
                idx = idx > 9 ? 9 : idx;
                atomicAdd(&g_sum[idx], (double)bce(x, tt));
                atomicAdd(&g_cnt[idx], 1u);
            }
        }
    }

    // drain own LDS atomics (barrier waits lgkmcnt), then read back own bins;
    // 64-lane tree reduce; block reduce; global atomics
    __syncthreads();
    float s[NB];
#pragma unroll
    for (int b = 0; b < NB; ++b) s[b] = slots[b];
#pragma unroll
    for (int off = 32; off > 0; off >>= 1) {
#pragma unroll
        for (int b = 0; b < NB; ++b) {
            s[b] += __shfl_down(s[b], off, 64);
            cnt[b] += __shfl_down(cnt[b], off, 64);
        }
    }

    __shared__ float w_sum[4][NB];
    __shared__ unsigned w_cnt[4][NB];
    const int wave = tid >> 6;
    const int lane = tid & 63;
    if (lane == 0) {
#pragma unroll
        for (int b = 0; b < NB; ++b) { w_sum[wave][b] = s[b]; w_cnt[wave][b] = cnt[b]; }
    }
    __syncthreads();
    if (tid < NB) {
        const float fs = w_sum[0][tid] + w_sum[1][tid] + w_sum[2][tid] + w_sum[3][tid];
        const unsigned fc = w_cnt[0][tid] + w_cnt[1][tid] + w_cnt[2][tid] + w_cnt[3][tid];
        atomicAdd(&g_sum[tid], (double)fs);
        atomicAdd(&g_cnt[tid], fc);
    }
}

__global__ void ghmc_final(const double* __restrict__ g_sum,
                           const unsigned int* __restrict__ g_cnt,
                           float* __restrict__ out) {
    if (blockIdx.x == 0 && threadIdx.x == 0) {
        double loss = 0.0;
        int n = 0;
#pragma unroll
        for (int b = 0; b < NB; ++b) {
            const unsigned c = g_cnt[b];
            if (c > 0u) {
                n += 1;
                loss += g_sum[b] / (double)c;
            }
        }
        loss /= (n > 0) ? (double)n : 1.0;
        out[0] = (float)loss;
    }
}

extern "C" void kernel_launch(void* const* d_in, const int* in_sizes, int n_in,
                              void* d_out, int out_size, void* d_ws, size_t ws_size,
                              hipStream_t stream) {
    const float* pred = (const float*)d_in[0];
    const float* tgt  = (const float*)d_in[1];
    long long ntot = (long long)in_sizes[0];
    int n4 = (int)(ntot / 4);

    double* g_sum = (double*)d_ws;                                  // 10 doubles
    unsigned int* g_cnt = (unsigned int*)((char*)d_ws + NB * sizeof(double));

    hipMemsetAsync(d_ws, 0, NB * sizeof(double) + NB * sizeof(unsigned int),
                   stream);

    const int threads = THREADS;
    const int blocks = 2048;  // chunk = 8192 float4/block = 128 KB window
    hipLaunchKernelGGL(ghmc_partial, dim3(blocks), dim3(threads), 0, stream,
                       (const float4*)pred, (const float4*)tgt, n4,
                       pred, tgt, ntot, g_sum, g_cnt);
    hipLaunchKernelGGL(ghmc_final, dim3(1), dim3(64), 0, stream,
                       g_sum, g_cnt, (float*)d_out);
}

// Round 2
// 526.352 us; speedup vs baseline: 1.3535x; 1.3535x over previous
//
#include <hip/hip_runtime.h>

// GHMC loss, round 7: revert r6's LDS atomics (370us — LDS atomic unit
// serializes scattered lane addresses). Root cause of the r5 167us plateau:
// per-element LDS read-modify-write on slots[idx] is a compiler-serialized
// RAW chain (runtime idx -> no alias disambiguation -> lgkmcnt(0) per put).
// Fix: accumulate the 10 bin sums in REGISTERS via a branchless select
// chain (all compile-time indices, 10-way ILP, no memory dependence).
// Bit-identical to r5: same addends, same per-thread element order
// (x + 0.0f is exact; bce >= 0 so no -0 edge cases).
//   loss = sum_b (S_b / C_b) / n_nonempty   (tot cancels algebraically)

#define THREADS 256
#define NB 10
#define PF 4         // prefetch group: 4 float4-pairs in flight

__device__ __forceinline__ float bce(float x, float t) {
    // max(x,0) - x*t + log1p(exp(-|x|)); hw v_exp/v_log ~2ulp, negligible
    return fmaxf(x, 0.0f) - x * t + __logf(1.0f + __expf(-fabsf(x)));
}

__global__ __launch_bounds__(THREADS) void ghmc_partial(
    const float4* __restrict__ p4, const float4* __restrict__ t4, int n4,
    const float* __restrict__ p1, const float* __restrict__ t1, long long ntot,
    double* __restrict__ g_sum, unsigned int* __restrict__ g_cnt) {

    const int tid = threadIdx.x;

    const float EDGE10 = 1.0f + 1e-6f;   // f32(edges[-1]) in the reference
    // 4 packed counters (one per float4 component): 10 six-bit fields each;
    // invalid elems go to bits 60..63 (never read). Flush before any field
    // can reach 63 increments.
    unsigned long long cc[4] = {0ull, 0ull, 0ull, 0ull};
    unsigned cnt[NB];
    float acc[NB];   // register bin sums — the r7 change
#pragma unroll
    for (int b = 0; b < NB; ++b) { cnt[b] = 0u; acc[b] = 0.0f; }

    // trunc(g*10) matches f32 searchsorted edges exactly (verified r3/r4,
    // absmax 0); g in [1.0,1+1e-6) -> idx 10 -> clamp 9 = reference bin 9.
    auto put = [&](float x, float t, unsigned long long& c) {
        const float g = fabsf(x - t);
        const float l = bce(x, t);
        int idx = (int)(g * 10.0f);
        idx = idx > 9 ? 9 : idx;
        idx = (g < EDGE10) ? idx : 10;   // 10 = discard (weight 0 in reference)
        c += 1ull << (6 * idx);
        // branchless register binning: 10 independent select+add chains,
        // compile-time indices (no scratch), no LDS, no RAW serialization
#pragma unroll
        for (int b = 0; b < NB; ++b)
            acc[b] += (idx == b) ? l : 0.0f;
    };
    auto flush_all = [&]() {
#pragma unroll
        for (int q = 0; q < 4; ++q) {
#pragma unroll
            for (int b = 0; b < NB; ++b)
                cnt[b] += (unsigned)((cc[q] >> (6 * b)) & 63ull);
            cc[q] = 0ull;
        }
    };

    // ---- block-contiguous partitioning ----
    const int chunk = (n4 + (int)gridDim.x - 1) / (int)gridDim.x;
    const int start = blockIdx.x * chunk;
    const int end = min(start + chunk, n4);
    const int count = max(end - start, 0);
    const int full = count / THREADS;        // full block-strided iters (32)
    const int ngrp = full / PF;              // prefetch groups (8)

    float4 PA[PF], TA[PF], PB[PF], TB[PF];
    auto loadg = [&](float4 (&Pd)[PF], float4 (&Td)[PF], int grp) {
#pragma unroll
        for (int g = 0; g < PF; ++g) {
            const int id = start + grp * PF * THREADS + g * THREADS + tid;
            Pd[g] = p4[id]; Td[g] = t4[id];
        }
    };
    auto proc = [&](float4 (&Pd)[PF], float4 (&Td)[PF]) {
#pragma unroll
        for (int g = 0; g < PF; ++g) {
            put(Pd[g].x, Td[g].x, cc[0]);
            put(Pd[g].y, Td[g].y, cc[1]);
            put(Pd[g].z, Td[g].z, cc[2]);
            put(Pd[g].w, Td[g].w, cc[3]);
        }
    };

    // static A/B ping-pong: every buffer index compile-time (no scratch),
    // one full proc (~hundreds of cycles) hides each group's HBM latency.
    int fcnt = 0;
    if (ngrp > 0) loadg(PA, TA, 0);
    int g2 = 0;
    for (; g2 + 2 <= ngrp; g2 += 2) {
        loadg(PB, TB, g2 + 1);
        proc(PA, TA);
        if (g2 + 2 < ngrp) loadg(PA, TA, g2 + 2);
        proc(PB, TB);
        fcnt += 2 * PF;
        if (fcnt >= 56) { flush_all(); fcnt = 0; }  // never taken at ngrp=8
    }
    if (g2 < ngrp) proc(PA, TA);             // odd ngrp tail (not taken here)

    // leftover full iters (full % PF) — not taken for this shape
    for (int k = ngrp * PF; k < full; ++k) {
        const int id = start + k * THREADS + tid;
        const float4 pp = p4[id], tt = t4[id];
        put(pp.x, tt.x, cc[0]); put(pp.y, tt.y, cc[1]);
        put(pp.z, tt.z, cc[2]); put(pp.w, tt.w, cc[3]);
    }
    // tail float4s within the chunk — not taken for this shape
    {
        const int id = start + full * THREADS + tid;
        if (id < end) {
            const float4 pp = p4[id], tt = t4[id];
            put(pp.x, tt.x, cc[0]); put(pp.y, tt.y, cc[1]);
            put(pp.z, tt.z, cc[2]); put(pp.w, tt.w, cc[3]);
        }
    }
    flush_all();

    // scalar tail for ntot % 4 (not taken here): direct global atomics
    if (blockIdx.x == 0 && tid == 0) {
        for (long long j = (long long)n4 * 4; j < ntot; ++j) {
            const float x = p1[j], tt = t1[j];
            const float g = fabsf(x - tt);
            if (g < EDGE10) {
                int idx = (int)(g * 10.0f);
                idx = idx > 9 ? 9 : idx;
                atomicAdd(&g_sum[idx], (double)bce(x, tt));
                atomicAdd(&g_cnt[idx], 1u);
            }
        }
    }

    // 64-lane tree reduce from registers; block reduce; global atomics
#pragma unroll
    for (int off = 32; off > 0; off >>= 1) {
#pragma unroll
        for (int b = 0; b < NB; ++b) {
            acc[b] += __shfl_down(acc[b], off, 64);
            cnt[b] += __shfl_down(cnt[b], off, 64);
        }
    }

    __shared__ float w_sum[4][NB];
    __shared__ unsigned w_cnt[4][NB];
    const int wave = tid >> 6;
    const int lane = tid & 63;
    if (lane == 0) {
#pragma unroll
        for (int b = 0; b < NB; ++b) { w_sum[wave][b] = acc[b]; w_cnt[wave][b] = cnt[b]; }
    }
    __syncthreads();
    if (tid < NB) {
        const float fs = w_sum[0][tid] + w_sum[1][tid] + w_sum[2][tid] + w_sum[3][tid];
        const unsigned fc = w_cnt[0][tid] + w_cnt[1][tid] + w_cnt[2][tid] + w_cnt[3][tid];
        atomicAdd(&g_sum[tid], (double)fs);
        atomicAdd(&g_cnt[tid], fc);
    }
}

__global__ void ghmc_final(const double* __restrict__ g_sum,
                           const unsigned int* __restrict__ g_cnt,
                           float* __restrict__ out) {
    if (blockIdx.x == 0 && threadIdx.x == 0) {
        double loss = 0.0;
        int n = 0;
#pragma unroll
        for (int b = 0; b < NB; ++b) {
            const unsigned c = g_cnt[b];
            if (c > 0u) {
                n += 1;
                loss += g_sum[b] / (double)c;
            }
        }
        loss /= (n > 0) ? (double)n : 1.0;
        out[0] = (float)loss;
    }
}

extern "C" void kernel_launch(void* const* d_in, const int* in_sizes, int n_in,
                              void* d_out, int out_size, void* d_ws, size_t ws_size,
                              hipStream_t stream) {
    const float* pred = (const float*)d_in[0];
    const float* tgt  = (const float*)d_in[1];
    long long ntot = (long long)in_sizes[0];
    int n4 = (int)(ntot / 4);

    double* g_sum = (double*)d_ws;                                  // 10 doubles
    unsigned int* g_cnt = (unsigned int*)((char*)d_ws + NB * sizeof(double));

    hipMemsetAsync(d_ws, 0, NB * sizeof(double) + NB * sizeof(unsigned int),
                   stream);

    const int threads = THREADS;
    const int blocks = 2048;  // chunk = 8192 float4/block = 128 KB window
    hipLaunchKernelGGL(ghmc_partial, dim3(blocks), dim3(threads), 0, stream,
                       (const float4*)pred, (const float4*)tgt, n4,
                       pred, tgt, ntot, g_sum, g_cnt);
    hipLaunchKernelGGL(ghmc_final, dim3(1), dim3(64), 0, stream,
                       g_sum, g_cnt, (float*)d_out);
}